// Round 5
// baseline (285.837 us; speedup 1.0000x reference)
//
#include <hip/hip_runtime.h>
#include <math.h>

typedef _Float16 h8 __attribute__((ext_vector_type(8)));
typedef float    f4 __attribute__((ext_vector_type(4)));

#define NPAIR (8*256*256)
#define NTILE (NPAIR/16)          // 32768 tiles of 16 rows
#define BLOCKS 2048
#define ITERS (NTILE/(BLOCKS*4))  // 4 tiles per wave

#define MFMA(a,b,c) __builtin_amdgcn_mfma_f32_16x16x32_f16((a),(b),(c),0,0,0)

// All weight fragments packed into one global array (h8 units):
// [0,256)    W1   [t*64+lane]          k 9..31 zero-padded
// [256,768)  W2   [c*256+t*64+lane]    k = 32c+8q+j
// [768,896)  Wg2  [c*64+lane]          n>=2 zero-padded
// [896,1920) Wg1  [c*256+t*64+lane]    k = 32c+8q+j (128 rows)
__device__ h8 g_all[1920];
__device__ float g_cc[2];         // C0 = sum ln_b*Wo, C1 = sum ln_g*Wo

__global__ void prep_kernel(const float* __restrict__ W1, const float* __restrict__ W2,
                            const float* __restrict__ Wg1, const float* __restrict__ Wg2,
                            const float* __restrict__ ln_g, const float* __restrict__ ln_b,
                            const float* __restrict__ Wo)
{
    int idx = blockIdx.x * 256 + threadIdx.x;
    if (idx < 256) {
        int t = idx >> 6, lane = idx & 63, q = lane >> 4, nn = lane & 15;
        h8 v;
#pragma unroll
        for (int j = 0; j < 8; ++j) { int k = 8*q + j; v[j] = (_Float16)((k < 9) ? W1[k*64 + 16*t + nn] : 0.f); }
        g_all[idx] = v;
    } else if (idx < 768) {
        int z = idx - 256; int c = z >> 8, t = (z >> 6) & 3, lane = z & 63, q = lane >> 4, nn = lane & 15;
        h8 v;
#pragma unroll
        for (int j = 0; j < 8; ++j) { int k = 32*c + 8*q + j; v[j] = (_Float16)W2[k*64 + 16*t + nn]; }
        g_all[idx] = v;
    } else if (idx < 896) {
        int z = idx - 768; int c = z >> 6, lane = z & 63, q = lane >> 4, nn = lane & 15;
        h8 v;
#pragma unroll
        for (int j = 0; j < 8; ++j) { int k = 32*c + 8*q + j; v[j] = (_Float16)((nn < 2) ? Wg2[k*2 + nn] : 0.f); }
        g_all[idx] = v;
    } else if (idx < 1920) {
        int z = idx - 896; int c = z >> 8, t = (z >> 6) & 3, lane = z & 63, q = lane >> 4, nn = lane & 15;
        h8 v;
#pragma unroll
        for (int j = 0; j < 8; ++j) { int k = 32*c + 8*q + j; v[j] = (_Float16)Wg1[k*64 + 16*t + nn]; }
        g_all[idx] = v;
    } else if (idx == 1920) {
        float c0 = 0.f, c1 = 0.f;
        for (int k = 0; k < 64; ++k) { c0 += ln_b[k]*Wo[k]; c1 += ln_g[k]*Wo[k]; }
        g_cc[0] = c0; g_cc[1] = c1;
    }
}

__device__ __forceinline__ float sig(float x) { return __builtin_amdgcn_rcpf(1.f + __expf(-x)); }

__device__ __forceinline__ f4 silu4(f4 v)
{
    f4 r; r[0] = v[0]*sig(v[0]); r[1] = v[1]*sig(v[1]); r[2] = v[2]*sig(v[2]); r[3] = v[3]*sig(v[3]);
    return r;
}

__device__ __forceinline__ f4 reduce16(f4 v)  // sum over the 16 lanes of each 16-group
{
#pragma unroll
    for (int m = 1; m < 16; m <<= 1) {
        v[0] += __shfl_xor(v[0], m); v[1] += __shfl_xor(v[1], m);
        v[2] += __shfl_xor(v[2], m); v[3] += __shfl_xor(v[3], m);
    }
    return v;
}

__device__ __forceinline__ void st72(_Float16* p, f4 v)   // C-frag -> LDS row stride 72 (144B, 16B-aligned)
{ p[0] = (_Float16)v[0]; p[72] = (_Float16)v[1]; p[144] = (_Float16)v[2]; p[216] = (_Float16)v[3]; }

__device__ __forceinline__ void st136(_Float16* p, f4 v)  // row stride 136 (272B, 16B-aligned)
{ p[0] = (_Float16)v[0]; p[136] = (_Float16)v[1]; p[272] = (_Float16)v[2]; p[408] = (_Float16)v[3]; }

// LDS: 30720 B weight pool (block-shared) + 4 waves * 4608 B scratch.
// h (4608B), e (4352B), g (2304B) tiles ALIAS the same wave region — DS ops
// are wave-ordered and each stage's reads precede the next stage's writes.
// Total 49152 B -> 3 blocks/CU = 12 waves/CU (R4 was 62976 -> 2 blocks, occ 20%).
__global__ __launch_bounds__(256, 3) void fused_kernel(
    const float* __restrict__ coords, const float* __restrict__ cost,
    const float* __restrict__ lscale, const float* __restrict__ b1,
    const float* __restrict__ b2, const float* __restrict__ fgam,
    const float* __restrict__ fbet, const float* __restrict__ bg1,
    const float* __restrict__ bg2, const float* __restrict__ gt,
    const float* __restrict__ lng, const float* __restrict__ Wo,
    const float* __restrict__ bo, float* __restrict__ out)
{
    __shared__ __align__(16) char smem[30720 + 4*4608];
    const int tid = threadIdx.x;
    const int wave = tid >> 6, lane = tid & 63;
    const int q = lane >> 4, nn = lane & 15;

    h8* wL = (h8*)smem;                       // 1920 h8 = 30720 B
    for (int z = tid; z < 1920; z += 256) wL[z] = g_all[z];
    __syncthreads();

    _Float16* U = (_Float16*)(smem + 30720 + wave*4608);  // aliased h/e/g tile

    // register-resident B-frags (w1:16, w2:32, wg2:8 VGPRs)
    h8 w1f0 = wL[lane],      w1f1 = wL[64+lane],  w1f2 = wL[128+lane], w1f3 = wL[192+lane];
    h8 w2f00 = wL[256+lane],     w2f01 = wL[320+lane], w2f02 = wL[384+lane], w2f03 = wL[448+lane];
    h8 w2f10 = wL[512+lane],     w2f11 = wL[576+lane], w2f12 = wL[640+lane], w2f13 = wL[704+lane];
    h8 wg2f0 = wL[768+lane],     wg2f1 = wL[832+lane];
    unsigned wg1o = 896;                      // laundered each iter to block LICM

    const float b1c0 = b1[nn], b1c1 = b1[16+nn], b1c2 = b1[32+nn], b1c3 = b1[48+nn];
    const float b2c0 = b2[nn], b2c1 = b2[16+nn], b2c2 = b2[32+nn], b2c3 = b2[48+nn];
    const float bgc0 = bg1[nn], bgc1 = bg1[16+nn], bgc2 = bg1[32+nn], bgc3 = bg1[48+nn];
    const float fg00 = fgam[nn], fg01 = fgam[16+nn], fg02 = fgam[32+nn], fg03 = fgam[48+nn];
    const float fg10 = fgam[64+nn], fg11 = fgam[80+nn], fg12 = fgam[96+nn], fg13 = fgam[112+nn];
    const float fb00 = fbet[nn], fb01 = fbet[16+nn], fb02 = fbet[32+nn], fb03 = fbet[48+nn];
    const float fb10 = fbet[64+nn], fb11 = fbet[80+nn], fb12 = fbet[96+nn], fb13 = fbet[112+nn];
    const float gw0 = lng[nn]*Wo[nn], gw1 = lng[16+nn]*Wo[16+nn];
    const float gw2 = lng[32+nn]*Wo[32+nn], gw3 = lng[48+nn]*Wo[48+nn];
    const float s0 = __expf(lscale[0]), s1 = __expf(lscale[1]);
    const float invT = __expf(-gt[0]);
    const float outc = g_cc[0] + bo[0], C1 = g_cc[1];
    const float lgb = (nn < 2) ? bg2[nn] : 0.f;

    const int wgid = blockIdx.x*4 + wave;

    for (int it = 0; it < ITERS; ++it) {
        const int T = wgid + it*(BLOCKS*4);
        const int p0 = T*16;
        const int bb = p0 >> 16, ii = (p0 >> 8) & 255, j0 = p0 & 255;
        // ---- features: every lane computes BOTH channels for its pair nn ----
        const float xc = cost[p0 + nn];
        const float* cb = coords + (bb << 9);
        const float xi = cb[2*ii], yi = cb[2*ii+1];
        const float xj = cb[2*(j0+nn)], yj = cb[2*(j0+nn)+1];
        const float xa = atan2f(yi - yj, xi - xj);
        const float c0v = xc*s0;
        const float c1v = __sinf(xc)*s0,      c2v = __cosf(xc)*s0;
        const float c3v = __sinf(2.f*xc)*s0,  c4v = __cosf(2.f*xc)*s0;
        const float c5v = __sinf(4.f*xc)*s0,  c6v = __cosf(4.f*xc)*s0;
        const float c7v = __sinf(8.f*xc)*s0,  c8v = __cosf(8.f*xc)*s0;
        const float a0v = xa*s1;
        const float a1v = __sinf(xa)*s1,      a2v = __cosf(xa)*s1;
        const float a3v = __sinf(2.f*xa)*s1,  a4v = __cosf(2.f*xa)*s1;
        const float a5v = __sinf(4.f*xa)*s1,  a6v = __cosf(4.f*xa)*s1;
        const float a7v = __sinf(8.f*xa)*s1,  a8v = __cosf(8.f*xa)*s1;
        // L1 A-frags built locally: lane(q,nn) holds feat[pair nn][k=8q+j]
        const bool q0 = (q == 0), q1 = (q == 1);
        h8 aF0, aF1;
        aF0[0] = (_Float16)(q0 ? c0v : (q1 ? c8v : 0.f));
        aF0[1] = (_Float16)(q0 ? c1v : 0.f); aF0[2] = (_Float16)(q0 ? c2v : 0.f);
        aF0[3] = (_Float16)(q0 ? c3v : 0.f); aF0[4] = (_Float16)(q0 ? c4v : 0.f);
        aF0[5] = (_Float16)(q0 ? c5v : 0.f); aF0[6] = (_Float16)(q0 ? c6v : 0.f);
        aF0[7] = (_Float16)(q0 ? c7v : 0.f);
        aF1[0] = (_Float16)(q0 ? a0v : (q1 ? a8v : 0.f));
        aF1[1] = (_Float16)(q0 ? a1v : 0.f); aF1[2] = (_Float16)(q0 ? a2v : 0.f);
        aF1[3] = (_Float16)(q0 ? a3v : 0.f); aF1[4] = (_Float16)(q0 ? a4v : 0.f);
        aF1[5] = (_Float16)(q0 ? a5v : 0.f); aF1[6] = (_Float16)(q0 ? a6v : 0.f);
        aF1[7] = (_Float16)(q0 ? a7v : 0.f);
        // ---- L1 -> silu -> h tile (U) ----
        _Float16* hw0 = U + q*288 + nn;
        _Float16* hw1 = U + 1152 + q*288 + nn;
        { f4 a = {b1c0,b1c0,b1c0,b1c0}; a = MFMA(aF0, w1f0, a); st72(hw0,    silu4(a)); }
        { f4 a = {b1c1,b1c1,b1c1,b1c1}; a = MFMA(aF0, w1f1, a); st72(hw0+16, silu4(a)); }
        { f4 a = {b1c2,b1c2,b1c2,b1c2}; a = MFMA(aF0, w1f2, a); st72(hw0+32, silu4(a)); }
        { f4 a = {b1c3,b1c3,b1c3,b1c3}; a = MFMA(aF0, w1f3, a); st72(hw0+48, silu4(a)); }
        { f4 a = {b1c0,b1c0,b1c0,b1c0}; a = MFMA(aF1, w1f0, a); st72(hw1,    silu4(a)); }
        { f4 a = {b1c1,b1c1,b1c1,b1c1}; a = MFMA(aF1, w1f1, a); st72(hw1+16, silu4(a)); }
        { f4 a = {b1c2,b1c2,b1c2,b1c2}; a = MFMA(aF1, w1f2, a); st72(hw1+32, silu4(a)); }
        { f4 a = {b1c3,b1c3,b1c3,b1c3}; a = MFMA(aF1, w1f3, a); st72(hw1+48, silu4(a)); }
        // ---- L2: h @ W2 + b2, FiLM; e in f32 frags + f16 into U (aliases h) ----
        h8 a00 = *(h8*)(U + nn*72 + q*8);
        h8 a01 = *(h8*)(U + nn*72 + 32 + q*8);
        h8 a10 = *(h8*)(U + 1152 + nn*72 + q*8);
        h8 a11 = *(h8*)(U + 1152 + nn*72 + 32 + q*8);
        _Float16* ew = U + q*544 + nn;
        f4 e00,e01,e02,e03,e10,e11,e12,e13;
        { f4 a={b2c0,b2c0,b2c0,b2c0}; a=MFMA(a00,w2f00,a); a=MFMA(a01,w2f10,a); e00=a*fg00+fb00; st136(ew,     e00); }
        { f4 a={b2c1,b2c1,b2c1,b2c1}; a=MFMA(a00,w2f01,a); a=MFMA(a01,w2f11,a); e01=a*fg01+fb01; st136(ew+16,  e01); }
        { f4 a={b2c2,b2c2,b2c2,b2c2}; a=MFMA(a00,w2f02,a); a=MFMA(a01,w2f12,a); e02=a*fg02+fb02; st136(ew+32,  e02); }
        { f4 a={b2c3,b2c3,b2c3,b2c3}; a=MFMA(a00,w2f03,a); a=MFMA(a01,w2f13,a); e03=a*fg03+fb03; st136(ew+48,  e03); }
        { f4 a={b2c0,b2c0,b2c0,b2c0}; a=MFMA(a10,w2f00,a); a=MFMA(a11,w2f10,a); e10=a*fg10+fb10; st136(ew+64,  e10); }
        { f4 a={b2c1,b2c1,b2c1,b2c1}; a=MFMA(a10,w2f01,a); a=MFMA(a11,w2f11,a); e11=a*fg11+fb11; st136(ew+80,  e11); }
        { f4 a={b2c2,b2c2,b2c2,b2c2}; a=MFMA(a10,w2f02,a); a=MFMA(a11,w2f12,a); e12=a*fg12+fb12; st136(ew+96,  e12); }
        { f4 a={b2c3,b2c3,b2c3,b2c3}; a=MFMA(a10,w2f03,a); a=MFMA(a11,w2f13,a); e13=a*fg13+fb13; st136(ew+112, e13); }
        // ---- gate1: [e0|e1] @ Wg1 + bg1 -> silu -> g tile (aliases e) ----
        h8 ae0 = *(h8*)(U + nn*136 + q*8);
        h8 ae1 = *(h8*)(U + nn*136 + 32 + q*8);
        h8 ae2 = *(h8*)(U + nn*136 + 64 + q*8);
        h8 ae3 = *(h8*)(U + nn*136 + 96 + q*8);
        asm volatile("" : "+s"(wg1o));        // block LICM of the 16 frag reads
        const h8* wgv = wL + wg1o;
        _Float16* gw_ = U + q*288 + nn;
        { f4 a={bgc0,bgc0,bgc0,bgc0}; a=MFMA(ae0,wgv[lane],a);     a=MFMA(ae1,wgv[256+lane],a); a=MFMA(ae2,wgv[512+lane],a); a=MFMA(ae3,wgv[768+lane],a); st72(gw_,    silu4(a)); }
        { f4 a={bgc1,bgc1,bgc1,bgc1}; a=MFMA(ae0,wgv[64+lane],a);  a=MFMA(ae1,wgv[320+lane],a); a=MFMA(ae2,wgv[576+lane],a); a=MFMA(ae3,wgv[832+lane],a); st72(gw_+16, silu4(a)); }
        { f4 a={bgc2,bgc2,bgc2,bgc2}; a=MFMA(ae0,wgv[128+lane],a); a=MFMA(ae1,wgv[384+lane],a); a=MFMA(ae2,wgv[640+lane],a); a=MFMA(ae3,wgv[896+lane],a); st72(gw_+32, silu4(a)); }
        { f4 a={bgc3,bgc3,bgc3,bgc3}; a=MFMA(ae0,wgv[192+lane],a); a=MFMA(ae1,wgv[448+lane],a); a=MFMA(ae2,wgv[704+lane],a); a=MFMA(ae3,wgv[960+lane],a); st72(gw_+48, silu4(a)); }
        // ---- gate2: g @ Wg2 (N pad 16); logits broadcast via shfl ----
        h8 ag0 = *(h8*)(U + nn*72 + q*8);
        h8 ag1 = *(h8*)(U + nn*72 + 32 + q*8);
        f4 lg = {lgb, lgb, lgb, lgb};
        lg = MFMA(ag0, wg2f0, lg); lg = MFMA(ag1, wg2f1, lg);
        const int sb = lane & 48;
        f4 w1v;
        w1v[0] = sig((__shfl(lg[0], sb|1) - __shfl(lg[0], sb))*invT);
        w1v[1] = sig((__shfl(lg[1], sb|1) - __shfl(lg[1], sb))*invT);
        w1v[2] = sig((__shfl(lg[2], sb|1) - __shfl(lg[2], sb))*invT);
        w1v[3] = sig((__shfl(lg[3], sb|1) - __shfl(lg[3], sb))*invT);
        // ---- fuse + LayerNorm + head (var = E[x^2] - mu^2) ----
        f4 fu0 = e00 + w1v*(e10-e00);
        f4 fu1 = e01 + w1v*(e11-e01);
        f4 fu2 = e02 + w1v*(e12-e02);
        f4 fu3 = e03 + w1v*(e13-e03);
        f4 sv = reduce16((fu0+fu1)+(fu2+fu3));
        f4 sq = reduce16((fu0*fu0+fu1*fu1)+(fu2*fu2+fu3*fu3));
        f4 dt = reduce16((fu0*gw0 + fu1*gw1) + (fu2*gw2 + fu3*gw3));
        f4 mu = sv * (1.f/64.f);
        f4 vv = sq * (1.f/64.f) - mu*mu;
        f4 rs;
        rs[0] = __builtin_amdgcn_rsqf(vv[0]+1e-5f); rs[1] = __builtin_amdgcn_rsqf(vv[1]+1e-5f);
        rs[2] = __builtin_amdgcn_rsqf(vv[2]+1e-5f); rs[3] = __builtin_amdgcn_rsqf(vv[3]+1e-5f);
        f4 o = rs*(dt - mu*C1) + outc;
        if (nn == 0) *(f4*)(out + p0 + q*4) = o;
    }
}

extern "C" void kernel_launch(void* const* d_in, const int* in_sizes, int n_in,
                              void* d_out, int out_size, void* d_ws, size_t ws_size,
                              hipStream_t stream)
{
    const float* coords = (const float*)d_in[0];
    const float* cost   = (const float*)d_in[1];
    const float* lscale = (const float*)d_in[2];
    const float* W1     = (const float*)d_in[3];
    const float* b1     = (const float*)d_in[4];
    const float* W2     = (const float*)d_in[5];
    const float* b2     = (const float*)d_in[6];
    const float* fg     = (const float*)d_in[7];
    const float* fb     = (const float*)d_in[8];
    const float* Wg1    = (const float*)d_in[9];
    const float* bg1    = (const float*)d_in[10];
    const float* Wg2    = (const float*)d_in[11];
    const float* bg2    = (const float*)d_in[12];
    const float* gt     = (const float*)d_in[13];
    const float* lng    = (const float*)d_in[14];
    const float* lnb    = (const float*)d_in[15];
    const float* Wo     = (const float*)d_in[16];
    const float* bo     = (const float*)d_in[17];
    float* out = (float*)d_out;

    prep_kernel<<<8, 256, 0, stream>>>(W1, W2, Wg1, Wg2, lng, lnb, Wo);
    fused_kernel<<<BLOCKS, 256, 0, stream>>>(
        coords, cost, lscale, b1, b2, fg, fb, bg1, bg2, gt, lng, Wo, bo, out);
}